// Round 11
// baseline (266.161 us; speedup 1.0000x reference)
//
#include <hip/hip_runtime.h>
#include <stdint.h>
#include <stddef.h>

#define EPS   1e-5f
#define CINCH 128
#define CI    64
#define NPIX  4096
#define KSPL  6
#define LOG2E 1.44269504088896340736f

typedef __bf16 bf16_t;
typedef _Float16 f16_t;
typedef bf16_t bf16x8 __attribute__((ext_vector_type(8)));
typedef f16_t  f16x8  __attribute__((ext_vector_type(8)));
typedef float  f32x4  __attribute__((ext_vector_type(4)));

__device__ __forceinline__ f32x4 mfma16(bf16x8 a, bf16x8 b, f32x4 c) {
  return __builtin_amdgcn_mfma_f32_16x16x32_bf16(a, b, c, 0, 0, 0);
}
__device__ __forceinline__ f32x4 fzero4() {
  f32x4 z = {0.f, 0.f, 0.f, 0.f};
  return z;
}

// ---------------------------------------------------------------------------
// Workspace (MiB offsets):
//   thetaT_h [B][N][64] bf16 (x LOG2E)   0
//   thetaT_l [B][N][64] bf16 (x LOG2E)   2
//   phiT_h   [B][N][64] bf16 PLAIN       4
//   phiT_l   [B][N][64] bf16 PLAIN       6
//   g_cm     [B][64][N] bf16 PLAIN       8
//   Opart    [B][6][N][64] f16          10   (12.6 MiB)
//   ml       [B][6][N][2]  f32          23   (0.79 MiB)
// All K/V consumed DIRECTLY from global (L2-resident, fragment-shaped
// wave loads = 16 fully-utilized 64B lines); no LDS staging, no barriers.
// ---------------------------------------------------------------------------

// ============ stage 1: fused theta/phi/g projections + x1 concat ============
// grid (128,4), 256 thr. Bias folded into acc BEFORE each barrier (bf[] is
// overwritten by the next loadW after it).
__global__ __launch_bounds__(256) void proj_all(
    const float* __restrict__ x1, const float* __restrict__ x2,
    const float* __restrict__ tw, const float* __restrict__ tb,
    const float* __restrict__ tg, const float* __restrict__ tbt,
    const float* __restrict__ tm, const float* __restrict__ tv,
    const float* __restrict__ pw, const float* __restrict__ pb,
    const float* __restrict__ pg, const float* __restrict__ pbt,
    const float* __restrict__ pm, const float* __restrict__ pv,
    const float* __restrict__ gw, const float* __restrict__ gb,
    const float* __restrict__ gg, const float* __restrict__ gbt,
    const float* __restrict__ gmn, const float* __restrict__ gv,
    bf16_t* __restrict__ thetaT_h, bf16_t* __restrict__ thetaT_l,
    bf16_t* __restrict__ phiT_h,   bf16_t* __restrict__ phiT_l,
    bf16_t* __restrict__ g_cm,     float* __restrict__ out)
{
  __shared__ float wT[CINCH][CI];                      // 32 KiB, per-phase
  __shared__ float bf[CI];
  __shared__ float xs[CINCH][32];                      // 16 KiB x tile
  __shared__ __align__(16) char tbuf[32 * 68 * 4];     // 8.7 KiB transpose
  float (*tF)[68] = (float(*)[68])tbuf;
  float (*gT)[33] = (float(*)[33])tbuf;

  const int tid = threadIdx.x;
  const int b   = blockIdx.y;
  const int n0  = blockIdx.x * 32;
  const int px  = tid & 31;
  const int og  = tid >> 5;

  auto loadW = [&](const float* w, const float* bb_, const float* gm_,
                   const float* bt_, const float* mn_, const float* vr_,
                   float mul) {
    for (int idx = tid; idx < CI * CINCH; idx += 256) {
      const int o = idx & 63, c = idx >> 6;
      const float sc = gm_[o] * rsqrtf(vr_[o] + EPS);
      wT[c][o] = w[o * CINCH + c] * sc * mul;
      if (c == 0) bf[o] = (bb_[o] * sc + bt_[o] - mn_[o] * sc) * mul;
    }
  };
  auto stageX = [&](const float* x) {
    const float* xsrc = x + (size_t)b * CINCH * NPIX + n0;
#pragma unroll
    for (int i = 0; i < 4; ++i) {
      const int idx = i * 256 + tid;
      const int c = idx >> 3, p = idx & 7;
      *(f32x4*)&xs[c][p * 4] = *(const f32x4*)(xsrc + (size_t)c * NPIX + p * 4);
    }
  };
  auto compute = [&](float* acc) {
#pragma unroll
    for (int j = 0; j < 8; ++j) acc[j] = 0.f;
#pragma unroll 4
    for (int c0 = 0; c0 < CINCH; c0 += 4) {
      float xv[4];
#pragma unroll
      for (int cc = 0; cc < 4; ++cc) xv[cc] = xs[c0 + cc][px];
#pragma unroll
      for (int cc = 0; cc < 4; ++cc) {
        const f32x4 w0 = *(const f32x4*)&wT[c0 + cc][og * 8];
        const f32x4 w1 = *(const f32x4*)&wT[c0 + cc][og * 8 + 4];
#pragma unroll
        for (int j = 0; j < 4; ++j) {
          acc[j]     += w0[j] * xv[cc];
          acc[j + 4] += w1[j] * xv[cc];
        }
      }
    }
#pragma unroll
    for (int j = 0; j < 8; ++j) acc[j] += bf[og * 8 + j];
  };
  auto storeHL = [&](bf16_t* dh, bf16_t* dl) {   // plain [n][64] rows
    const int px2 = tid >> 3, ogs = tid & 7;
    bf16x8 hv, lv;
#pragma unroll
    for (int j = 0; j < 8; ++j) {
      const float v = tF[px2][ogs * 8 + j];
      const bf16_t h = (bf16_t)v;
      hv[j] = h;
      lv[j] = (bf16_t)(v - (float)h);
    }
    const size_t base = ((size_t)b * NPIX + n0 + px2) * CI + ogs * 8;
    *(bf16x8*)(dh + base) = hv;
    *(bf16x8*)(dl + base) = lv;
  };

  float acc[8];

  // ---- phase theta ----
  loadW(tw, tb, tg, tbt, tm, tv, LOG2E);
  {  // stage x1 + fused concat copy (out channels [128,256) = x1)
    const float* xsrc = x1 + (size_t)b * CINCH * NPIX + n0;
    float* odst = out + ((size_t)b * 256 + 128) * NPIX + n0;
#pragma unroll
    for (int i = 0; i < 4; ++i) {
      const int idx = i * 256 + tid;
      const int c = idx >> 3, p = idx & 7;
      const f32x4 v = *(const f32x4*)(xsrc + (size_t)c * NPIX + p * 4);
      *(f32x4*)&xs[c][p * 4] = v;
      *(f32x4*)(odst + (size_t)c * NPIX + p * 4) = v;
    }
  }
  __syncthreads();                       // s0
  compute(acc);
  __syncthreads();                       // s1
#pragma unroll
  for (int j = 0; j < 8; ++j) tF[px][og * 8 + j] = acc[j];
  loadW(pw, pb, pg, pbt, pm, pv, 1.f);
  stageX(x2);
  __syncthreads();                       // s2
  storeHL(thetaT_h, thetaT_l);

  // ---- phase phi ----
  compute(acc);
  __syncthreads();                       // s3
#pragma unroll
  for (int j = 0; j < 8; ++j) tF[px][og * 8 + j] = acc[j];
  loadW(gw, gb, gg, gbt, gmn, gv, 1.f);
  __syncthreads();                       // s4
  storeHL(phiT_h, phiT_l);

  // ---- phase g ----
  compute(acc);
  __syncthreads();                       // s5
#pragma unroll
  for (int j = 0; j < 8; ++j) gT[og * 8 + j][px] = acc[j];
  __syncthreads();                       // s6
  {
    const int c = tid & 63, mgp = tid >> 6;
    bf16x8 gvv;
#pragma unroll
    for (int j = 0; j < 8; ++j) gvv[j] = (bf16_t)gT[c][mgp * 8 + j];
    *(bf16x8*)(g_cm + ((size_t)b * CI + c) * NPIX + n0 + mgp * 8) = gvv;
  }
}

// ========================= stage 2: flash attention =========================
// Grid: 768 = B(4) x qt(32) x ks(6). Block: 256 (4 waves x 32 q). KBLK=64.
// BARRIER-FREE: K/V fragments loaded directly from global (L2-resident);
// only the per-wave P buffer lives in LDS (16 KiB/block).
__global__ __launch_bounds__(256, 3) void flash_attn(
    const bf16_t* __restrict__ thetaT_h, const bf16_t* __restrict__ thetaT_l,
    const bf16_t* __restrict__ phiT_h,   const bf16_t* __restrict__ phiT_l,
    const bf16_t* __restrict__ g_cm,
    f16_t* __restrict__ Opart, float* __restrict__ mlbuf)
{
  __shared__ __attribute__((aligned(16))) char sP[4][4096];   // per-wave

  const int tid  = threadIdx.x;
  const int lane = tid & 63;
  const int wid  = tid >> 6;
  const int lrow = lane & 15;
  const int lhi  = lane >> 4;

  const int wg = blockIdx.x;
  const int b  = wg / 192;
  const int rr = wg % 192;
  const int qt = rr / KSPL;
  const int ks = rr % KSPL;
  const int q0 = qt * 128 + wid * 32;
  const int t0 = (ks * 64) / KSPL;       // 64 key-tiles of 64 keys
  const int t1 = ((ks + 1) * 64) / KSPL;

  // per-lane fragment base pointers (row = key resp. channel, plain layout)
  const bf16_t* const phH = phiT_h + ((size_t)b * NPIX + lrow) * CI + lhi * 8;
  const bf16_t* const phL = phiT_l + ((size_t)b * NPIX + lrow) * CI + lhi * 8;
  const bf16_t* const gvb = g_cm + ((size_t)b * CI + lrow) * NPIX + lhi * 8;

  // Q fragments (theta pre-scaled by LOG2E), h & l splits
  bf16x8 qh[2][2], qlv[2][2];
  {
    const bf16_t* qbh = thetaT_h + ((size_t)b * NPIX + q0 + lrow) * CI + lhi * 8;
    const bf16_t* qbl = thetaT_l + ((size_t)b * NPIX + q0 + lrow) * CI + lhi * 8;
#pragma unroll
    for (int nt = 0; nt < 2; ++nt)
#pragma unroll
      for (int kk = 0; kk < 2; ++kk) {
        qh[nt][kk]  = *(const bf16x8*)(qbh + nt * 16 * CI + kk * 32);
        qlv[nt][kk] = *(const bf16x8*)(qbl + nt * 16 * CI + kk * 32);
      }
  }

  f32x4 oacc[2][4];
#pragma unroll
  for (int a = 0; a < 2; ++a)
#pragma unroll
    for (int c = 0; c < 4; ++c) oacc[a][c] = fzero4();

  float m_run[2] = {-1e30f, -1e30f};
  float l_run[2] = {0.f, 0.f};

  char* const Pw = sP[wid];

  for (int t = t0; t < t1; ++t) {
    const int key0 = t * 64;

    // ---- QK: per-mt direct fragment loads + MFMA (log2 domain, bf16x3) ----
    f32x4 s[4][2];
#pragma unroll
    for (int mt = 0; mt < 4; ++mt)
#pragma unroll
      for (int nt = 0; nt < 2; ++nt) s[mt][nt] = fzero4();

#pragma unroll
    for (int mt = 0; mt < 4; ++mt) {
      const size_t roff = (size_t)(key0 + mt * 16) * CI;
      bf16x8 aH0 = *(const bf16x8*)(phH + roff);
      bf16x8 aH1 = *(const bf16x8*)(phH + roff + 32);
      bf16x8 aL0 = *(const bf16x8*)(phL + roff);
      bf16x8 aL1 = *(const bf16x8*)(phL + roff + 32);
      __builtin_amdgcn_s_setprio(1);
#pragma unroll
      for (int nt = 0; nt < 2; ++nt) {
        s[mt][nt] = mfma16(aH0, qh[nt][0],  s[mt][nt]);
        s[mt][nt] = mfma16(aH0, qlv[nt][0], s[mt][nt]);
        s[mt][nt] = mfma16(aL0, qh[nt][0],  s[mt][nt]);
        s[mt][nt] = mfma16(aH1, qh[nt][1],  s[mt][nt]);
        s[mt][nt] = mfma16(aH1, qlv[nt][1], s[mt][nt]);
        s[mt][nt] = mfma16(aL1, qh[nt][1],  s[mt][nt]);
      }
      __builtin_amdgcn_s_setprio(0);
    }

    // ---- V fragments: issue now; softmax below covers their L2 latency ----
    bf16x8 bV[2][4];
#pragma unroll
    for (int ct = 0; ct < 4; ++ct)
#pragma unroll
      for (int kk = 0; kk < 2; ++kk)
        bV[kk][ct] = *(const bf16x8*)(gvb + (size_t)ct * 16 * NPIX +
                                      key0 + kk * 32);

    // ---- online softmax (exp2 domain); defer O-rescale (THR=5) ----
    float mx[2], a2[2];
#pragma unroll
    for (int nt = 0; nt < 2; ++nt) {
      float m1 = fmaxf(fmaxf(s[0][nt][0], s[0][nt][1]), fmaxf(s[0][nt][2], s[0][nt][3]));
      float m2 = fmaxf(fmaxf(s[1][nt][0], s[1][nt][1]), fmaxf(s[1][nt][2], s[1][nt][3]));
      float m3 = fmaxf(fmaxf(s[2][nt][0], s[2][nt][1]), fmaxf(s[2][nt][2], s[2][nt][3]));
      float m4 = fmaxf(fmaxf(s[3][nt][0], s[3][nt][1]), fmaxf(s[3][nt][2], s[3][nt][3]));
      float m = fmaxf(fmaxf(m1, m2), fmaxf(m3, m4));
      m = fmaxf(m, __shfl_xor(m, 16));
      m = fmaxf(m, __shfl_xor(m, 32));
      mx[nt] = m;
    }
    const bool up = !__all((mx[0] <= m_run[0] + 5.f) && (mx[1] <= m_run[1] + 5.f));
#pragma unroll
    for (int nt = 0; nt < 2; ++nt) {
      const float mnew  = up ? fmaxf(m_run[nt], mx[nt]) : m_run[nt];
      const float alpha = up ? exp2f(m_run[nt] - mnew) : 1.f;
      float lsum = 0.f;
#pragma unroll
      for (int mt = 0; mt < 4; ++mt)
#pragma unroll
        for (int r = 0; r < 4; ++r) {
          const float p = exp2f(s[mt][nt][r] - mnew);
          s[mt][nt][r] = p;
          lsum += p;
        }
      lsum += __shfl_xor(lsum, 16);
      lsum += __shfl_xor(lsum, 32);
      l_run[nt] = l_run[nt] * alpha + lsum;
      m_run[nt] = mnew;
      a2[nt] = alpha;
    }

    if (up) {
#pragma unroll
      for (int qt2 = 0; qt2 < 2; ++qt2) {
#pragma unroll
        for (int r = 0; r < 4; ++r) {
          const float av = __shfl(a2[qt2], lhi * 4 + r);
#pragma unroll
          for (int ct = 0; ct < 4; ++ct) oacc[qt2][ct][r] *= av;
        }
      }
    }

    // ---- pack P (bf16) into per-wave LDS [32 q][128B], XOR-swizzled ----
#pragma unroll
    for (int mt = 0; mt < 4; ++mt)
#pragma unroll
      for (int nt = 0; nt < 2; ++nt) {
        union { bf16_t h[4]; uint32_t u[2]; } pk;
#pragma unroll
        for (int r = 0; r < 4; ++r) pk.h[r] = (bf16_t)s[mt][nt][r];
        const int q    = nt * 16 + lrow;
        const int mloc = mt * 16 + lhi * 4;
        const int byte = q * 128 + ((mloc * 2) ^ ((q & 7) << 4));
        *(uint2*)(Pw + byte) = make_uint2(pk.u[0], pk.u[1]);
      }

    // ---- PV: O[q][c] += P[q][m] * V[m][c] (same-wave LDS, no barrier) ----
    __builtin_amdgcn_s_setprio(1);
#pragma unroll
    for (int qt2 = 0; qt2 < 2; ++qt2) {
      const int q = qt2 * 16 + lrow;
#pragma unroll
      for (int kk = 0; kk < 2; ++kk) {
        const bf16x8 pfrag =
            *(const bf16x8*)(Pw + q * 128 + ((kk * 64 + lhi * 16) ^ ((q & 7) << 4)));
#pragma unroll
        for (int ct = 0; ct < 4; ++ct)
          oacc[qt2][ct] = mfma16(pfrag, bV[kk][ct], oacc[qt2][ct]);
      }
    }
    __builtin_amdgcn_s_setprio(0);
  }

  // ---- epilogue: coalesced unnormalized partial O (f16) via per-wave LDS --
  {
#pragma unroll
    for (int qt2 = 0; qt2 < 2; ++qt2)
#pragma unroll
      for (int ct = 0; ct < 4; ++ct)
#pragma unroll
        for (int r = 0; r < 4; ++r) {
          const int ql = qt2 * 16 + lhi * 4 + r;
          const int c  = ct * 16 + lrow;
          *(f16_t*)(Pw + (ql * 64 + c) * 2) = (f16_t)oacc[qt2][ct][r];
        }
    f16_t* const Ob = Opart + ((size_t)(b * KSPL + ks) * NPIX + q0) * 64;
#pragma unroll
    for (int i = 0; i < 4; ++i) {
      const int idx = i * 64 + lane;        // 256 chunks of 16B, contiguous
      *(f16x8*)(Ob + idx * 8) = *(const f16x8*)(Pw + idx * 16);
    }
  }
  if (lhi < 2) {
    const int q = q0 + lhi * 16 + lrow;
    const size_t base = ((size_t)(b * KSPL + ks) * NPIX + q) * 2;
    mlbuf[base]     = m_run[lhi];
    mlbuf[base + 1] = l_run[lhi];
  }
}

// ========================= stage 3: merge + wout + BN =======================
__global__ __launch_bounds__(256) void merge_out(
    const f16_t* __restrict__ Opart, const float* __restrict__ mlbuf,
    const float* __restrict__ ww,  const float* __restrict__ wb,
    const float* __restrict__ wg,  const float* __restrict__ wbt,
    const float* __restrict__ wm,  const float* __restrict__ wvv,
    float* __restrict__ out)
{
  __shared__ float wlds[128][64];
  __shared__ float bfw[128];
  __shared__ float mrg[32][68];

  const int tid = threadIdx.x;
  const int b   = blockIdx.y;
  const int n0  = blockIdx.x * 32;

  for (int idx = tid; idx < 128 * 64; idx += 256) {
    const int o = idx >> 6, c = idx & 63;
    const float sc = wg[o] * rsqrtf(wvv[o] + EPS);
    wlds[o][c] = ww[o * 64 + c] * sc;
    if (c == 0) bfw[o] = wb[o] * sc + wbt[o] - wm[o] * sc;
  }

  {
    const int px = tid & 31;
    const int cg = tid >> 5;
    const int q  = n0 + px;
    float mk[KSPL], lk[KSPL];
#pragma unroll
    for (int ks = 0; ks < KSPL; ++ks) {
      const size_t base = ((size_t)(b * KSPL + ks) * NPIX + q) * 2;
      mk[ks] = mlbuf[base];
      lk[ks] = mlbuf[base + 1];
    }
    float M = mk[0];
#pragma unroll
    for (int ks = 1; ks < KSPL; ++ks) M = fmaxf(M, mk[ks]);
    float al[KSPL]; float den = 0.f;
#pragma unroll
    for (int ks = 0; ks < KSPL; ++ks) { al[ks] = exp2f(mk[ks] - M); den += al[ks] * lk[ks]; }
    const float inv = 1.f / den;
#pragma unroll
    for (int ks = 0; ks < KSPL; ++ks) al[ks] *= inv;

    float r[8];
#pragma unroll
    for (int j = 0; j < 8; ++j) r[j] = 0.f;
#pragma unroll
    for (int ks = 0; ks < KSPL; ++ks) {
      const f16x8 p = *(const f16x8*)(Opart +
          ((size_t)(b * KSPL + ks) * NPIX + q) * 64 + cg * 8);
#pragma unroll
      for (int j = 0; j < 8; ++j) r[j] += (float)p[j] * al[ks];
    }
#pragma unroll
    for (int j = 0; j < 8; ++j) mrg[px][cg * 8 + j] = r[j];
  }
  __syncthreads();

  const int px = tid & 31;
  const int oh = tid >> 5;
  float acc[16];
#pragma unroll
  for (int j = 0; j < 16; ++j) acc[j] = 0.f;

#pragma unroll 4
  for (int c0 = 0; c0 < 64; c0 += 4) {
    const f32x4 m4 = *(const f32x4*)&mrg[px][c0];
#pragma unroll
    for (int j = 0; j < 16; ++j) {
      const f32x4 w4 = *(const f32x4*)&wlds[oh * 16 + j][c0];
      acc[j] += w4[0] * m4[0] + w4[1] * m4[1] + w4[2] * m4[2] + w4[3] * m4[3];
    }
  }
#pragma unroll
  for (int j = 0; j < 16; ++j) {
    const int o = oh * 16 + j;
    out[((size_t)b * 256 + o) * NPIX + n0 + px] = acc[j] + bfw[o];
  }
}

// ============================== launcher ====================================
extern "C" void kernel_launch(void* const* d_in, const int* in_sizes, int n_in,
                              void* d_out, int out_size, void* d_ws, size_t ws_size,
                              hipStream_t stream) {
  (void)in_sizes; (void)n_in; (void)out_size; (void)ws_size;
  const float* x1  = (const float*)d_in[0];
  const float* x2  = (const float*)d_in[1];
  const float* tw  = (const float*)d_in[2];
  const float* tb  = (const float*)d_in[3];
  const float* tg  = (const float*)d_in[4];
  const float* tbt = (const float*)d_in[5];
  const float* tm  = (const float*)d_in[6];
  const float* tv  = (const float*)d_in[7];
  const float* pw  = (const float*)d_in[8];
  const float* pb  = (const float*)d_in[9];
  const float* pg  = (const float*)d_in[10];
  const float* pbt = (const float*)d_in[11];
  const float* pm  = (const float*)d_in[12];
  const float* pv  = (const float*)d_in[13];
  const float* gw  = (const float*)d_in[14];
  const float* gb  = (const float*)d_in[15];
  const float* gg  = (const float*)d_in[16];
  const float* gbt = (const float*)d_in[17];
  const float* gmn = (const float*)d_in[18];
  const float* gv  = (const float*)d_in[19];
  const float* ww  = (const float*)d_in[20];
  const float* wb  = (const float*)d_in[21];
  const float* wg  = (const float*)d_in[22];
  const float* wbt = (const float*)d_in[23];
  const float* wm  = (const float*)d_in[24];
  const float* wv  = (const float*)d_in[25];

  float* out = (float*)d_out;
  char*  ws  = (char*)d_ws;
  bf16_t* thetaT_h = (bf16_t*)(ws);
  bf16_t* thetaT_l = (bf16_t*)(ws + (size_t)(2)  * 1048576);
  bf16_t* phiT_h   = (bf16_t*)(ws + (size_t)(4)  * 1048576);
  bf16_t* phiT_l   = (bf16_t*)(ws + (size_t)(6)  * 1048576);
  bf16_t* g_cm     = (bf16_t*)(ws + (size_t)(8)  * 1048576);
  f16_t*  Opart    = (f16_t*) (ws + (size_t)(10) * 1048576);
  float*  mlbuf    = (float*) (ws + (size_t)(23) * 1048576);

  dim3 gp(128, 4);
  proj_all<<<gp, 256, 0, stream>>>(x1, x2,
                                   tw, tb, tg, tbt, tm, tv,
                                   pw, pb, pg, pbt, pm, pv,
                                   gw, gb, gg, gbt, gmn, gv,
                                   thetaT_h, thetaT_l, phiT_h, phiT_l,
                                   g_cm, out);
  flash_attn<<<768, 256, 0, stream>>>(thetaT_h, thetaT_l, phiT_h, phiT_l,
                                      g_cm, Opart, mlbuf);
  merge_out<<<gp, 256, 0, stream>>>(Opart, mlbuf, ww, wb, wg, wbt, wm, wv, out);
}